// Round 5
// baseline (375.106 us; speedup 1.0000x reference)
//
#include <hip/hip_runtime.h>
#include <hip/hip_bf16.h>
#include <hip/hip_cooperative_groups.h>
#include <math.h>

namespace cg = cooperative_groups;

#define EDIM 256
#define HDIM 256
#define BDIM 64
#define TDIM 2048
#define NC   64
#define TC   32
#define CPB  4      // chunks per persistent block

typedef __attribute__((ext_vector_type(8)))  short  short8;
typedef __attribute__((ext_vector_type(4)))  float  floatx4;
typedef __attribute__((ext_vector_type(4)))  unsigned int uintx4;

__device__ __forceinline__ unsigned short f2bf(float f) {
    unsigned int u = __float_as_uint(f);
    u += 0x7FFFu + ((u >> 16) & 1u);      // RNE
    return (unsigned short)(u >> 16);
}
__device__ __forceinline__ unsigned int pk2(float a, float b) {
    return (unsigned int)f2bf(a) | ((unsigned int)f2bf(b) << 16);
}
__device__ __forceinline__ float sigm(float x) {
    return __builtin_amdgcn_rcpf(1.f + __expf(-x));
}
__device__ __forceinline__ float tanh_fast(float x) {
    return fmaf(-2.f, __builtin_amdgcn_rcpf(1.f + __expf(2.f * x)), 1.f);
}

// ---------------- Fused cooperative kernel ----------------
// Phase A: pack Wp (fragment order) + convert emb -> bf16.
// Phase B: persistent MFMA gates + per-chunk recurrence composition.
// Phase C: combine chunks + o-gate + output dot (blocks 0..63).
__global__ __launch_bounds__(256, 2) void qrnn_fused(
    const int* __restrict__ X, const float* __restrict__ emb,
    unsigned short* __restrict__ ebf, unsigned short* __restrict__ Wp,
    const float* __restrict__ bq, const float* __restrict__ c0,
    const float* __restrict__ Wq, const float* __restrict__ Wout,
    const float* __restrict__ bout, float* __restrict__ wsA,
    float* __restrict__ wsB, float* __restrict__ out)
{
    __shared__ __align__(16) short Bsh[32768];   // 64 KB
    cg::grid_group grid = cg::this_grid();

    const int tid = threadIdx.x;
    const int bx  = blockIdx.x;                  // 0..511
    const int lane = tid & 63, w = tid >> 6;
    const int col = lane & 15, q = lane >> 4;

    // ---- Phase A ----
    if (bx < 256) {
        // Wp[hg][nt][ks][lane][8]: value = Wq[(ks*32+q*8+j)*768 + c]
        const int nt = (bx >> 3) & 7;
        const int hg = bx >> 6;
        const int ks = bx & 7;
        const int plane = tid >> 2, pj = tid & 3;
        const int pcol = plane & 15, pq = plane >> 4;
        const int h = hg * 64 + (nt & 3) * 16 + pcol;
        const int c = (nt < 4) ? h : (HDIM + h);
        const int k = ks * 32 + pq * 8 + pj * 2;
        unsigned int v = pk2(Wq[k * (3 * HDIM) + c], Wq[(k + 1) * (3 * HDIM) + c]);
        *(unsigned int*)(Wp + (size_t)bx * 512 + plane * 8 + pj * 2) = v;
    }
#pragma unroll
    for (int it = 0; it < 8; ++it) {
        int gidx = it * 131072 + bx * 256 + tid;    // group of 8 elems
        if (gidx < 1024000) {
            size_t i = (size_t)gidx * 8;
            floatx4 a = *(const floatx4*)(emb + i);
            floatx4 b = *(const floatx4*)(emb + i + 4);
            uintx4 o = {pk2(a.x, a.y), pk2(a.z, a.w), pk2(b.x, b.y), pk2(b.z, b.w)};
            *(uintx4*)(ebf + i) = o;
        }
    }

    __threadfence();
    grid.sync();

    // ---- Phase B ----
    {
        const int cgi = bx & 15, bg = (bx >> 4) & 7, hg = bx >> 7;

        // Stage B slice (64 KB, all ks) once.
        const unsigned short* wpb = Wp + (size_t)hg * 32768;
#pragma unroll
        for (int i = 0; i < 16; ++i) {
            const int ch = w * 16 + i;          // wave-uniform
            __builtin_amdgcn_global_load_lds(
                (const __attribute__((address_space(1))) unsigned int*)(wpb + ch * 512 + lane * 8),
                (__attribute__((address_space(3))) unsigned int*)(Bsh + ch * 512),
                16, 0, 0);
        }

        const int b0 = bg * 8 + 2 * w;
        int xid[CPB][4];
#pragma unroll
        for (int c = 0; c < CPB; ++c)
#pragma unroll
            for (int mt = 0; mt < 4; ++mt)
                xid[c][mt] = X[(b0 + (mt >> 1)) * TDIM + (cgi * CPB + c) * TC + (mt & 1) * 16 + col];

        const int hbase = hg * 64;
        float bz[4], bff[4];
#pragma unroll
        for (int nt = 0; nt < 4; ++nt) {
            bz[nt]  = bq[hbase + nt * 16 + col];
            bff[nt] = bq[HDIM + hbase + nt * 16 + col];
        }

        short8 abuf[4][4];
        auto fetchA = [&](int c, int ks, int slot) {
#pragma unroll
            for (int mt = 0; mt < 4; ++mt)
                abuf[slot][mt] = *(const short8*)(ebf + (size_t)xid[c][mt] * EDIM + q * 8 + ks * 32);
        };

        floatx4 acc[4][8];
#pragma unroll
        for (int mt = 0; mt < 4; ++mt)
#pragma unroll
            for (int nt = 0; nt < 8; ++nt) acc[mt][nt] = (floatx4){0.f, 0.f, 0.f, 0.f};

        fetchA(0, 0, 0);
        fetchA(0, 1, 1);
        fetchA(0, 2, 2);
        __syncthreads();   // waits LDS staging too

#pragma unroll
        for (int c = 0; c < CPB; ++c) {
#pragma unroll
            for (int ks = 0; ks < 8; ++ks) {
                const int s = c * 8 + ks;
                if (s + 3 < CPB * 8)
                    fetchA((s + 3) >> 3, (s + 3) & 7, (s + 3) & 3);
                const int sl = s & 3;
#pragma unroll
                for (int nh = 0; nh < 2; ++nh) {      // halves cut peak VGPR pressure
                    short8 bf[4];
#pragma unroll
                    for (int j = 0; j < 4; ++j)
                        bf[j] = *(const short8*)(Bsh + ((nh * 4 + j) * 8 + ks) * 512 + lane * 8);
#pragma unroll
                    for (int j = 0; j < 4; ++j)
#pragma unroll
                        for (int mt = 0; mt < 4; ++mt)
                            acc[mt][nh * 4 + j] = __builtin_amdgcn_mfma_f32_16x16x32_bf16(
                                abuf[sl][mt], bf[j], acc[mt][nh * 4 + j], 0, 0, 0);
                }
            }

            // Epilogue: t = q*4 + j (+16*(mt&1)), h-col = nt*16+col; z: nt, f: nt+4.
            const int cc = cgi * CPB + c;
            float Af0[4], Bf0[4], Af1[4], Bf1[4];
#pragma unroll
            for (int nt = 0; nt < 4; ++nt) {
                float Aseg[4], Bseg[4];
#pragma unroll
                for (int mt = 0; mt < 4; ++mt) {
                    float Ac = 1.f, Bc = 0.f;
#pragma unroll
                    for (int j = 0; j < 4; ++j) {
                        float z = tanh_fast(acc[mt][nt][j] + bz[nt]);
                        float f = sigm(acc[mt][nt + 4][j] + bff[nt]);
                        Ac = f * Ac;
                        Bc = fmaf(f, Bc, (1.f - f) * z);
                    }
                    Aseg[mt] = Ac; Bseg[mt] = Bc;
                }
#pragma unroll
                for (int st = 0; st < 2; ++st) {
                    const int msk = 16 << st;
                    const bool self_earlier = ((q >> st) & 1) == 0;
#pragma unroll
                    for (int mt = 0; mt < 4; ++mt) {
                        float Ap = __shfl_xor(Aseg[mt], msk, 64);
                        float Bp = __shfl_xor(Bseg[mt], msk, 64);
                        Bseg[mt] = self_earlier ? fmaf(Ap, Bseg[mt], Bp)
                                                : fmaf(Aseg[mt], Bp, Bseg[mt]);
                        Aseg[mt] = Aseg[mt] * Ap;
                    }
                }
                Af0[nt] = Aseg[0] * Aseg[1];
                Bf0[nt] = fmaf(Aseg[1], Bseg[0], Bseg[1]);
                Af1[nt] = Aseg[2] * Aseg[3];
                Bf1[nt] = fmaf(Aseg[3], Bseg[2], Bseg[3]);
            }

            float As0 = (q == 0) ? Af0[0] : (q == 1) ? Af0[1] : (q == 2) ? Af0[2] : Af0[3];
            float Bs0 = (q == 0) ? Bf0[0] : (q == 1) ? Bf0[1] : (q == 2) ? Bf0[2] : Bf0[3];
            float As1 = (q == 0) ? Af1[0] : (q == 1) ? Af1[1] : (q == 2) ? Af1[2] : Af1[3];
            float Bs1 = (q == 0) ? Bf1[0] : (q == 1) ? Bf1[1] : (q == 2) ? Bf1[2] : Bf1[3];

            const size_t r0 = ((size_t)cc * BDIM + b0) * HDIM + hbase + lane;
            wsA[r0] = As0;          wsB[r0] = Bs0;
            wsA[r0 + HDIM] = As1;   wsB[r0 + HDIM] = Bs1;

#pragma unroll
            for (int mt = 0; mt < 4; ++mt)
#pragma unroll
                for (int nt = 0; nt < 8; ++nt) acc[mt][nt] = (floatx4){0.f, 0.f, 0.f, 0.f};
        }
    }

    __threadfence();
    grid.sync();

    // ---- Phase C ----
    if (bx < BDIM) {
        const int b = bx;
        const int h = tid;

        float c = c0[b * HDIM + h];
        for (int c8 = 0; c8 < NC; c8 += 8) {
            float a[8], bb[8];
#pragma unroll
            for (int i = 0; i < 8; ++i) {
                size_t base = ((size_t)(c8 + i) * BDIM + b) * HDIM + h;
                a[i]  = wsA[base];
                bb[i] = wsB[base];
            }
#pragma unroll
            for (int i = 0; i < 8; ++i) c = fmaf(a[i], c, bb[i]);
        }

        float* xs  = (float*)Bsh;          // reuse LDS
        float* red = xs + EDIM;
        int idx = X[b * TDIM + (TDIM - 1)];
        xs[h] = emb[(size_t)idx * EDIM + h];
        __syncthreads();

        float acc2 = 0.f;
#pragma unroll 16
        for (int e = 0; e < EDIM; ++e)
            acc2 = fmaf(xs[e], Wq[e * (3 * HDIM) + 2 * HDIM + h], acc2);

        float o  = 1.f / (1.f + expf(-(acc2 + bq[2 * HDIM + h])));
        float hn = o * c;

        red[h] = hn * Wout[h];
        __syncthreads();
        for (int s = HDIM / 2; s > 0; s >>= 1) {
            if (h < s) red[h] += red[h + s];
            __syncthreads();
        }
        if (h == 0) out[b] = red[0] + bout[0];
    }
}

// ---------------- Non-cooperative fallback (round-4 path) ----------------
__global__ __launch_bounds__(256) void qrnn_pack_fb(
    const float* __restrict__ Wq, unsigned short* __restrict__ Wp)
{
    const int bx = blockIdx.x;
    const int nt = (bx >> 3) & 7;
    const int hg = bx >> 6;
    const int ks = bx & 7;
    const int t = threadIdx.x;
    const int lane = t >> 2, pj = t & 3;
    const int col = lane & 15, q = lane >> 4;
    const int h = hg * 64 + (nt & 3) * 16 + col;
    const int c = (nt < 4) ? h : (HDIM + h);
    const int k = ks * 32 + q * 8 + pj * 2;
    unsigned int v = pk2(Wq[k * (3 * HDIM) + c], Wq[(k + 1) * (3 * HDIM) + c]);
    *(unsigned int*)(Wp + (size_t)bx * 512 + lane * 8 + pj * 2) = v;
}

__global__ __launch_bounds__(256, 2) void qrnn_mfma_fb(
    const int* __restrict__ X, const float* __restrict__ emb,
    const unsigned short* __restrict__ Wp, const float* __restrict__ bq,
    float* __restrict__ wsA, float* __restrict__ wsB)
{
    __shared__ __align__(16) short Bsh[32768];
    const int tid = threadIdx.x;
    const int cgi = blockIdx.x, bg = blockIdx.y, hg = blockIdx.z;
    const int lane = tid & 63, w = tid >> 6;
    const int col = lane & 15, q = lane >> 4;

    const unsigned short* wpb = Wp + (size_t)hg * 32768;
#pragma unroll
    for (int i = 0; i < 16; ++i) {
        const int ch = w * 16 + i;
        __builtin_amdgcn_global_load_lds(
            (const __attribute__((address_space(1))) unsigned int*)(wpb + ch * 512 + lane * 8),
            (__attribute__((address_space(3))) unsigned int*)(Bsh + ch * 512),
            16, 0, 0);
    }

    const int b0 = bg * 8 + 2 * w;
    int xid[CPB][4];
#pragma unroll
    for (int c = 0; c < CPB; ++c)
#pragma unroll
        for (int mt = 0; mt < 4; ++mt)
            xid[c][mt] = X[(b0 + (mt >> 1)) * TDIM + (cgi * CPB + c) * TC + (mt & 1) * 16 + col];

    const int hbase = hg * 64;
    float bz[4], bff[4];
#pragma unroll
    for (int nt = 0; nt < 4; ++nt) {
        bz[nt]  = bq[hbase + nt * 16 + col];
        bff[nt] = bq[HDIM + hbase + nt * 16 + col];
    }

    short8 abuf[4][4];
    auto fetchA = [&](int c, int ks, int slot) {
#pragma unroll
        for (int mt = 0; mt < 4; ++mt) {
            const float* ap = emb + (size_t)xid[c][mt] * EDIM + q * 8 + ks * 32;
            floatx4 f0 = *(const floatx4*)ap;
            floatx4 f1 = *(const floatx4*)(ap + 4);
            uintx4 p = {pk2(f0.x, f0.y), pk2(f0.z, f0.w),
                        pk2(f1.x, f1.y), pk2(f1.z, f1.w)};
            abuf[slot][mt] = *(short8*)&p;
        }
    };

    floatx4 acc[4][8];
#pragma unroll
    for (int mt = 0; mt < 4; ++mt)
#pragma unroll
        for (int nt = 0; nt < 8; ++nt) acc[mt][nt] = (floatx4){0.f, 0.f, 0.f, 0.f};

    fetchA(0, 0, 0);
    fetchA(0, 1, 1);
    fetchA(0, 2, 2);
    __syncthreads();

#pragma unroll
    for (int c = 0; c < CPB; ++c) {
#pragma unroll
        for (int ks = 0; ks < 8; ++ks) {
            const int s = c * 8 + ks;
            if (s + 3 < CPB * 8)
                fetchA((s + 3) >> 3, (s + 3) & 7, (s + 3) & 3);
            const int sl = s & 3;
#pragma unroll
            for (int nh = 0; nh < 2; ++nh) {
                short8 bf[4];
#pragma unroll
                for (int j = 0; j < 4; ++j)
                    bf[j] = *(const short8*)(Bsh + ((nh * 4 + j) * 8 + ks) * 512 + lane * 8);
#pragma unroll
                for (int j = 0; j < 4; ++j)
#pragma unroll
                    for (int mt = 0; mt < 4; ++mt)
                        acc[mt][nh * 4 + j] = __builtin_amdgcn_mfma_f32_16x16x32_bf16(
                            abuf[sl][mt], bf[j], acc[mt][nh * 4 + j], 0, 0, 0);
            }
        }

        const int cc = cgi * CPB + c;
        float Af0[4], Bf0[4], Af1[4], Bf1[4];
#pragma unroll
        for (int nt = 0; nt < 4; ++nt) {
            float Aseg[4], Bseg[4];
#pragma unroll
            for (int mt = 0; mt < 4; ++mt) {
                float Ac = 1.f, Bc = 0.f;
#pragma unroll
                for (int j = 0; j < 4; ++j) {
                    float z = tanh_fast(acc[mt][nt][j] + bz[nt]);
                    float f = sigm(acc[mt][nt + 4][j] + bff[nt]);
                    Ac = f * Ac;
                    Bc = fmaf(f, Bc, (1.f - f) * z);
                }
                Aseg[mt] = Ac; Bseg[mt] = Bc;
            }
#pragma unroll
            for (int st = 0; st < 2; ++st) {
                const int msk = 16 << st;
                const bool self_earlier = ((q >> st) & 1) == 0;
#pragma unroll
                for (int mt = 0; mt < 4; ++mt) {
                    float Ap = __shfl_xor(Aseg[mt], msk, 64);
                    float Bp = __shfl_xor(Bseg[mt], msk, 64);
                    Bseg[mt] = self_earlier ? fmaf(Ap, Bseg[mt], Bp)
                                            : fmaf(Aseg[mt], Bp, Bseg[mt]);
                    Aseg[mt] = Aseg[mt] * Ap;
                }
            }
            Af0[nt] = Aseg[0] * Aseg[1];
            Bf0[nt] = fmaf(Aseg[1], Bseg[0], Bseg[1]);
            Af1[nt] = Aseg[2] * Aseg[3];
            Bf1[nt] = fmaf(Aseg[3], Bseg[2], Bseg[3]);
        }

        float As0 = (q == 0) ? Af0[0] : (q == 1) ? Af0[1] : (q == 2) ? Af0[2] : Af0[3];
        float Bs0 = (q == 0) ? Bf0[0] : (q == 1) ? Bf0[1] : (q == 2) ? Bf0[2] : Bf0[3];
        float As1 = (q == 0) ? Af1[0] : (q == 1) ? Af1[1] : (q == 2) ? Af1[2] : Af1[3];
        float Bs1 = (q == 0) ? Bf1[0] : (q == 1) ? Bf1[1] : (q == 2) ? Bf1[2] : Bf1[3];

        const size_t r0 = ((size_t)cc * BDIM + b0) * HDIM + hbase + lane;
        wsA[r0] = As0;          wsB[r0] = Bs0;
        wsA[r0 + HDIM] = As1;   wsB[r0 + HDIM] = Bs1;

#pragma unroll
        for (int mt = 0; mt < 4; ++mt)
#pragma unroll
            for (int nt = 0; nt < 8; ++nt) acc[mt][nt] = (floatx4){0.f, 0.f, 0.f, 0.f};
    }
}

__global__ __launch_bounds__(256) void qrnn_combine_fb(
    const float* __restrict__ wsA, const float* __restrict__ wsB,
    const float* __restrict__ c0, const int* __restrict__ X,
    const float* __restrict__ emb, const float* __restrict__ Wq,
    const float* __restrict__ bq, const float* __restrict__ Wout,
    const float* __restrict__ bout, float* __restrict__ out)
{
    const int b = blockIdx.x;
    const int h = threadIdx.x;

    float c = c0[b * HDIM + h];
    for (int c8 = 0; c8 < NC; c8 += 8) {
        float a[8], bb[8];
#pragma unroll
        for (int i = 0; i < 8; ++i) {
            size_t base = ((size_t)(c8 + i) * BDIM + b) * HDIM + h;
            a[i]  = wsA[base];
            bb[i] = wsB[base];
        }
#pragma unroll
        for (int i = 0; i < 8; ++i) c = fmaf(a[i], c, bb[i]);
    }

    __shared__ float xs[EDIM];
    int idx = X[b * TDIM + (TDIM - 1)];
    xs[h] = emb[(size_t)idx * EDIM + h];
    __syncthreads();

    float acc = 0.f;
#pragma unroll 16
    for (int e = 0; e < EDIM; ++e)
        acc = fmaf(xs[e], Wq[e * (3 * HDIM) + 2 * HDIM + h], acc);

    float o  = 1.f / (1.f + expf(-(acc + bq[2 * HDIM + h])));
    float hn = o * c;

    __shared__ float red[HDIM];
    red[h] = hn * Wout[h];
    __syncthreads();
    for (int s = HDIM / 2; s > 0; s >>= 1) {
        if (h < s) red[h] += red[h + s];
        __syncthreads();
    }
    if (h == 0) out[b] = red[0] + bout[0];
}

extern "C" void kernel_launch(void* const* d_in, const int* in_sizes, int n_in,
                              void* d_out, int out_size, void* d_ws, size_t ws_size,
                              hipStream_t stream) {
    const int*   X    = (const int*)d_in[0];
    const float* emb  = (const float*)d_in[1];
    const float* Wq   = (const float*)d_in[2];
    const float* bq   = (const float*)d_in[3];
    const float* c0   = (const float*)d_in[4];
    const float* Wout = (const float*)d_in[5];
    const float* bout = (const float*)d_in[6];
    float* out = (float*)d_out;

    float* wsA = (float*)d_ws;                        // [NC][B][H]
    float* wsB = wsA + (size_t)NC * BDIM * HDIM;      // [NC][B][H]
    unsigned short* Wp  = (unsigned short*)(wsB + (size_t)NC * BDIM * HDIM);  // 256 KB
    unsigned short* ebf = Wp + (size_t)256 * 512;     // 16.4 MB

    const size_t need_full = (size_t)2 * NC * BDIM * HDIM * 4
                           + (size_t)256 * 512 * 2
                           + (size_t)32000 * EDIM * 2;
    const bool full = ws_size >= need_full;

    bool done = false;
    if (full) {
        void* args[] = {(void*)&X, (void*)&emb, (void*)&ebf, (void*)&Wp,
                        (void*)&bq, (void*)&c0, (void*)&Wq, (void*)&Wout,
                        (void*)&bout, (void*)&wsA, (void*)&wsB, (void*)&out};
        hipError_t e = hipLaunchCooperativeKernel(
            reinterpret_cast<void*>(qrnn_fused), dim3(512), dim3(256),
            args, 0, stream);
        done = (e == hipSuccess);
    }

    if (!done) {
        qrnn_pack_fb<<<256, 256, 0, stream>>>(Wq, Wp);
        dim3 g(NC / CPB, BDIM / 8, HDIM / 64);
        qrnn_mfma_fb<<<g, 256, 0, stream>>>(X, emb, Wp, bq, wsA, wsB);
        qrnn_combine_fb<<<BDIM, 256, 0, stream>>>(wsA, wsB, c0, X, emb, Wq, bq, Wout, bout, out);
    }
}

// Round 6
// 267.441 us; speedup vs baseline: 1.4026x; 1.4026x over previous
//
#include <hip/hip_runtime.h>
#include <hip/hip_bf16.h>
#include <math.h>

#define EDIM 256
#define HDIM 256
#define BDIM 64
#define TDIM 2048
#define NC   64
#define TC   32
#define CPB  4      // chunks per persistent block

typedef __attribute__((ext_vector_type(8)))  short  short8;
typedef __attribute__((ext_vector_type(4)))  float  floatx4;
typedef __attribute__((ext_vector_type(4)))  unsigned int uintx4;

__device__ __forceinline__ unsigned short f2bf(float f) {
    unsigned int u = __float_as_uint(f);
    u += 0x7FFFu + ((u >> 16) & 1u);      // RNE
    return (unsigned short)(u >> 16);
}
__device__ __forceinline__ unsigned int pk2(float a, float b) {
    return (unsigned int)f2bf(a) | ((unsigned int)f2bf(b) << 16);
}
__device__ __forceinline__ float sigm(float x) {
    return __builtin_amdgcn_rcpf(1.f + __expf(-x));
}
__device__ __forceinline__ float tanh_fast(float x) {
    return fmaf(-2.f, __builtin_amdgcn_rcpf(1.f + __expf(2.f * x)), 1.f);
}

// Main: persistent block = 4 chunks x 8 batches x 64 h (128 n-cols: z||f).
// W fragment-packed fp32->bf16 INTO LDS in-kernel (once per block, amortized
// over 4 chunks) - no separate pack dispatch, no Wp buffer.
// A gathered per-lane as fp32 from emb, packed to bf16 in-register,
// 3-slot ring / distance-2 software pipeline crossing chunk boundaries.
__global__ __launch_bounds__(256, 2) void qrnn_mfma(
    const int* __restrict__ X, const float* __restrict__ emb,
    const float* __restrict__ Wq, const float* __restrict__ bq,
    float* __restrict__ wsA, float* __restrict__ wsB)
{
    __shared__ __align__(16) short Bsh[32768];   // 64 KB: [nt][ks][lane][8]

    const int tid = threadIdx.x;
    const int cgi = blockIdx.x, bg = blockIdx.y, hg = blockIdx.z;
    const int lane = tid & 63, w = tid >> 6;
    const int col = lane & 15, q = lane >> 4;
    const int hbase = hg * 64;

    // ---- In-kernel W fragment pack: Bsh[sb=nt*8+ks][plane][pj] ----
    // value = bf16(Wq[(ks*32 + pq*8 + pj*2 (+1))*768 + c]),
    // c = z: hbase+(nt&3)*16+pcol, f: 256 + same. (index math proven in r2-r5 pack)
    {
        const int plane = tid >> 2, pj = tid & 3;
        const int pcol = plane & 15, pq = plane >> 4;
#pragma unroll 4
        for (int sb = 0; sb < 64; ++sb) {
            const int nt = sb >> 3, ks = sb & 7;
            const int h = hbase + (nt & 3) * 16 + pcol;
            const int c = (nt < 4) ? h : (HDIM + h);
            const int k = ks * 32 + pq * 8 + pj * 2;
            unsigned int v = pk2(Wq[k * (3 * HDIM) + c], Wq[(k + 1) * (3 * HDIM) + c]);
            *(unsigned int*)(Bsh + sb * 512 + plane * 8 + pj * 2) = v;
        }
    }

    const int b0 = bg * 8 + 2 * w;
    int xid[CPB][4];
#pragma unroll
    for (int c = 0; c < CPB; ++c)
#pragma unroll
        for (int mt = 0; mt < 4; ++mt)
            xid[c][mt] = X[(b0 + (mt >> 1)) * TDIM + (cgi * CPB + c) * TC + (mt & 1) * 16 + col];

    float bz[4], bff[4];
#pragma unroll
    for (int nt = 0; nt < 4; ++nt) {
        bz[nt]  = bq[hbase + nt * 16 + col];
        bff[nt] = bq[HDIM + hbase + nt * 16 + col];
    }

    short8 abuf[3][4];
    auto fetchA = [&](int c, int ks, int slot) {
#pragma unroll
        for (int mt = 0; mt < 4; ++mt) {
            const float* ap = emb + (size_t)xid[c][mt] * EDIM + q * 8 + ks * 32;
            floatx4 f0 = *(const floatx4*)ap;
            floatx4 f1 = *(const floatx4*)(ap + 4);
            uintx4 p = {pk2(f0.x, f0.y), pk2(f0.z, f0.w),
                        pk2(f1.x, f1.y), pk2(f1.z, f1.w)};
            abuf[slot][mt] = *(short8*)&p;
        }
    };

    floatx4 acc[4][8];
#pragma unroll
    for (int mt = 0; mt < 4; ++mt)
#pragma unroll
        for (int nt = 0; nt < 8; ++nt) acc[mt][nt] = (floatx4){0.f, 0.f, 0.f, 0.f};

    fetchA(0, 0, 0);
    fetchA(0, 1, 1);
    __syncthreads();   // W pack visible to all waves

#pragma unroll
    for (int c = 0; c < CPB; ++c) {
#pragma unroll
        for (int ks = 0; ks < 8; ++ks) {
            const int s = c * 8 + ks;
            if (s + 2 < CPB * 8)
                fetchA((s + 2) >> 3, (s + 2) & 7, (s + 2) % 3);
            const int sl = s % 3;
#pragma unroll
            for (int nh = 0; nh < 2; ++nh) {      // halves cut peak VGPR pressure
                short8 bf[4];
#pragma unroll
                for (int j = 0; j < 4; ++j)
                    bf[j] = *(const short8*)(Bsh + ((nh * 4 + j) * 8 + ks) * 512 + lane * 8);
#pragma unroll
                for (int j = 0; j < 4; ++j)
#pragma unroll
                    for (int mt = 0; mt < 4; ++mt)
                        acc[mt][nh * 4 + j] = __builtin_amdgcn_mfma_f32_16x16x32_bf16(
                            abuf[sl][mt], bf[j], acc[mt][nh * 4 + j], 0, 0, 0);
            }
        }

        // Epilogue: t = q*4 + j (+16*(mt&1)), h-col = nt*16+col; z: nt, f: nt+4.
        const int cc = cgi * CPB + c;
        float Af0[4], Bf0[4], Af1[4], Bf1[4];
#pragma unroll
        for (int nt = 0; nt < 4; ++nt) {
            float Aseg[4], Bseg[4];
#pragma unroll
            for (int mt = 0; mt < 4; ++mt) {
                float Ac = 1.f, Bc = 0.f;
#pragma unroll
                for (int j = 0; j < 4; ++j) {
                    float z = tanh_fast(acc[mt][nt][j] + bz[nt]);
                    float f = sigm(acc[mt][nt + 4][j] + bff[nt]);
                    Ac = f * Ac;
                    Bc = fmaf(f, Bc, (1.f - f) * z);
                }
                Aseg[mt] = Ac; Bseg[mt] = Bc;
            }
#pragma unroll
            for (int st = 0; st < 2; ++st) {
                const int msk = 16 << st;
                const bool self_earlier = ((q >> st) & 1) == 0;
#pragma unroll
                for (int mt = 0; mt < 4; ++mt) {
                    float Ap = __shfl_xor(Aseg[mt], msk, 64);
                    float Bp = __shfl_xor(Bseg[mt], msk, 64);
                    Bseg[mt] = self_earlier ? fmaf(Ap, Bseg[mt], Bp)
                                            : fmaf(Aseg[mt], Bp, Bseg[mt]);
                    Aseg[mt] = Aseg[mt] * Ap;
                }
            }
            Af0[nt] = Aseg[0] * Aseg[1];
            Bf0[nt] = fmaf(Aseg[1], Bseg[0], Bseg[1]);
            Af1[nt] = Aseg[2] * Aseg[3];
            Bf1[nt] = fmaf(Aseg[3], Bseg[2], Bseg[3]);
        }

        float As0 = (q == 0) ? Af0[0] : (q == 1) ? Af0[1] : (q == 2) ? Af0[2] : Af0[3];
        float Bs0 = (q == 0) ? Bf0[0] : (q == 1) ? Bf0[1] : (q == 2) ? Bf0[2] : Bf0[3];
        float As1 = (q == 0) ? Af1[0] : (q == 1) ? Af1[1] : (q == 2) ? Af1[2] : Af1[3];
        float Bs1 = (q == 0) ? Bf1[0] : (q == 1) ? Bf1[1] : (q == 2) ? Bf1[2] : Bf1[3];

        const size_t r0 = ((size_t)cc * BDIM + b0) * HDIM + hbase + lane;
        wsA[r0] = As0;          wsB[r0] = Bs0;
        wsA[r0 + HDIM] = As1;   wsB[r0 + HDIM] = Bs1;

#pragma unroll
        for (int mt = 0; mt < 4; ++mt)
#pragma unroll
            for (int nt = 0; nt < 8; ++nt) acc[mt][nt] = (floatx4){0.f, 0.f, 0.f, 0.f};
    }
}

// Combine chunk (A,B) pairs + o-gate at t=T-1 + output dot.
__global__ __launch_bounds__(256) void qrnn_combine(
    const float* __restrict__ wsA, const float* __restrict__ wsB,
    const float* __restrict__ c0, const int* __restrict__ X,
    const float* __restrict__ emb, const float* __restrict__ Wq,
    const float* __restrict__ bq, const float* __restrict__ Wout,
    const float* __restrict__ bout, float* __restrict__ out)
{
    const int b = blockIdx.x;
    const int h = threadIdx.x;

    float c = c0[b * HDIM + h];
    for (int c8 = 0; c8 < NC; c8 += 8) {
        float a[8], bb[8];
#pragma unroll
        for (int i = 0; i < 8; ++i) {
            size_t base = ((size_t)(c8 + i) * BDIM + b) * HDIM + h;
            a[i]  = wsA[base];
            bb[i] = wsB[base];
        }
#pragma unroll
        for (int i = 0; i < 8; ++i) c = fmaf(a[i], c, bb[i]);
    }

    __shared__ float xs[EDIM];
    int idx = X[b * TDIM + (TDIM - 1)];
    xs[h] = emb[(size_t)idx * EDIM + h];
    __syncthreads();

    float acc = 0.f;
#pragma unroll 16
    for (int e = 0; e < EDIM; ++e)
        acc = fmaf(xs[e], Wq[e * (3 * HDIM) + 2 * HDIM + h], acc);

    float o  = 1.f / (1.f + expf(-(acc + bq[2 * HDIM + h])));
    float hn = o * c;

    __shared__ float red[HDIM];
    red[h] = hn * Wout[h];
    __syncthreads();
    for (int s = HDIM / 2; s > 0; s >>= 1) {
        if (h < s) red[h] += red[h + s];
        __syncthreads();
    }
    if (h == 0) out[b] = red[0] + bout[0];
}

extern "C" void kernel_launch(void* const* d_in, const int* in_sizes, int n_in,
                              void* d_out, int out_size, void* d_ws, size_t ws_size,
                              hipStream_t stream) {
    const int*   X    = (const int*)d_in[0];
    const float* emb  = (const float*)d_in[1];
    const float* Wq   = (const float*)d_in[2];
    const float* bq   = (const float*)d_in[3];
    const float* c0   = (const float*)d_in[4];
    const float* Wout = (const float*)d_in[5];
    const float* bout = (const float*)d_in[6];
    float* out = (float*)d_out;

    float* wsA = (float*)d_ws;                        // [NC][B][H]
    float* wsB = wsA + (size_t)NC * BDIM * HDIM;      // [NC][B][H]  (8 MB total)

    dim3 g(NC / CPB, BDIM / 8, HDIM / 64);   // 16 x 8 x 4 = 512 blocks (2/CU)
    qrnn_mfma<<<g, 256, 0, stream>>>(X, emb, Wq, bq, wsA, wsB);
    qrnn_combine<<<BDIM, 256, 0, stream>>>(wsA, wsB, c0, X, emb, Wq, bq, Wout, bout, out);
}

// Round 7
// 158.343 us; speedup vs baseline: 2.3689x; 1.6890x over previous
//
#include <hip/hip_runtime.h>
#include <hip/hip_bf16.h>
#include <math.h>

#define EDIM 256
#define HDIM 256
#define BDIM 64
#define TDIM 2048
#define NC   64
#define TC   32
#define CPB  4      // chunks per persistent block

typedef __attribute__((ext_vector_type(8)))  short  short8;
typedef __attribute__((ext_vector_type(4)))  float  floatx4;
typedef __attribute__((ext_vector_type(4)))  unsigned int uintx4;

__device__ __forceinline__ unsigned short f2bf(float f) {
    unsigned int u = __float_as_uint(f);
    u += 0x7FFFu + ((u >> 16) & 1u);      // RNE
    return (unsigned short)(u >> 16);
}
__device__ __forceinline__ unsigned int pk2(float a, float b) {
    return (unsigned int)f2bf(a) | ((unsigned int)f2bf(b) << 16);
}
__device__ __forceinline__ float sigm(float x) {
    return __builtin_amdgcn_rcpf(1.f + __expf(-x));
}
__device__ __forceinline__ float tanh_fast(float x) {
    return fmaf(-2.f, __builtin_amdgcn_rcpf(1.f + __expf(2.f * x)), 1.f);
}

// Fused pack: blocks [0,256) -> Wp fragment-pack; blocks [256,4256) -> emb bf16.
// Wp layout: [hg][nt][ks][lane][8] bf16; value = Wq[(ks*32+q*8+j)*768 + c],
// c = z: hg*64+(nt&3)*16+col, f: 256 + same.
__global__ __launch_bounds__(256) void qrnn_pack(
    const float* __restrict__ Wq, const float* __restrict__ emb,
    unsigned short* __restrict__ Wp, unsigned short* __restrict__ ebf)
{
    const int bx = blockIdx.x;
    if (bx < 256) {
        const int nt = (bx >> 3) & 7;
        const int hg = bx >> 6;
        const int ks = bx & 7;
        const int t = threadIdx.x;
        const int lane = t >> 2, pj = t & 3;
        const int col = lane & 15, q = lane >> 4;
        const int h = hg * 64 + (nt & 3) * 16 + col;
        const int c = (nt < 4) ? h : (HDIM + h);
        const int k = ks * 32 + q * 8 + pj * 2;
        unsigned int v = pk2(Wq[k * (3 * HDIM) + c], Wq[(k + 1) * (3 * HDIM) + c]);
        *(unsigned int*)(Wp + (size_t)bx * 512 + lane * 8 + pj * 2) = v;
    } else {
        size_t i = ((size_t)(bx - 256) * 256 + threadIdx.x) * 8;
        floatx4 a = *(const floatx4*)(emb + i);
        floatx4 b = *(const floatx4*)(emb + i + 4);
        uintx4 o = {pk2(a.x, a.y), pk2(a.z, a.w), pk2(b.x, b.y), pk2(b.z, b.w)};
        *(uintx4*)(ebf + i) = o;
    }
}

// Main: persistent block = 4 chunks x 8 batches x 64 h (128 n-cols: z||f).
// B (weights) staged to LDS ONCE per block via global_load_lds; chunk loop is
// barrier-free. A gathered per-lane from bf16 emb, 3-slot ring / distance-2
// software pipeline crossing chunk boundaries.
template<bool EMBBF>
__global__ __launch_bounds__(256, 2) void qrnn_mfma(
    const int* __restrict__ X, const float* __restrict__ emb,
    const unsigned short* __restrict__ ebf, const unsigned short* __restrict__ Wp,
    const float* __restrict__ bq, float* __restrict__ wsA, float* __restrict__ wsB)
{
    __shared__ __align__(16) short Bsh[32768];   // 64 KB: [nt][ks][lane][8]

    const int tid = threadIdx.x;
    const int cgi = blockIdx.x, bg = blockIdx.y, hg = blockIdx.z;
    const int lane = tid & 63, w = tid >> 6;
    const int col = lane & 15, q = lane >> 4;

    // Stage B slice (64 KB, all ks) once.
    const unsigned short* wpb = Wp + (size_t)hg * 32768;
#pragma unroll
    for (int i = 0; i < 16; ++i) {
        const int ch = w * 16 + i;          // wave-uniform
        __builtin_amdgcn_global_load_lds(
            (const __attribute__((address_space(1))) unsigned int*)(wpb + ch * 512 + lane * 8),
            (__attribute__((address_space(3))) unsigned int*)(Bsh + ch * 512),
            16, 0, 0);
    }

    const int b0 = bg * 8 + 2 * w;
    int xid[CPB][4];
#pragma unroll
    for (int c = 0; c < CPB; ++c)
#pragma unroll
        for (int mt = 0; mt < 4; ++mt)
            xid[c][mt] = X[(b0 + (mt >> 1)) * TDIM + (cgi * CPB + c) * TC + (mt & 1) * 16 + col];

    const int hbase = hg * 64;
    float bz[4], bff[4];
#pragma unroll
    for (int nt = 0; nt < 4; ++nt) {
        bz[nt]  = bq[hbase + nt * 16 + col];
        bff[nt] = bq[HDIM + hbase + nt * 16 + col];
    }

    short8 abuf[3][4];
    auto fetchA = [&](int c, int ks, int slot) {
#pragma unroll
        for (int mt = 0; mt < 4; ++mt) {
            if constexpr (EMBBF) {
                abuf[slot][mt] = *(const short8*)(ebf + (size_t)xid[c][mt] * EDIM + q * 8 + ks * 32);
            } else {
                const float* ap = emb + (size_t)xid[c][mt] * EDIM + q * 8 + ks * 32;
                floatx4 f0 = *(const floatx4*)ap;
                floatx4 f1 = *(const floatx4*)(ap + 4);
                uintx4 p = {pk2(f0.x, f0.y), pk2(f0.z, f0.w),
                            pk2(f1.x, f1.y), pk2(f1.z, f1.w)};
                abuf[slot][mt] = *(short8*)&p;
            }
        }
    };

    floatx4 acc[4][8];
#pragma unroll
    for (int mt = 0; mt < 4; ++mt)
#pragma unroll
        for (int nt = 0; nt < 8; ++nt) acc[mt][nt] = (floatx4){0.f, 0.f, 0.f, 0.f};

    fetchA(0, 0, 0);
    fetchA(0, 1, 1);
    __syncthreads();   // waits LDS staging too

#pragma unroll
    for (int c = 0; c < CPB; ++c) {
#pragma unroll
        for (int ks = 0; ks < 8; ++ks) {
            const int s = c * 8 + ks;
            if (s + 2 < CPB * 8)
                fetchA((s + 2) >> 3, (s + 2) & 7, (s + 2) % 3);
            const int sl = s % 3;
#pragma unroll
            for (int nh = 0; nh < 2; ++nh) {      // halves cut peak VGPR pressure
                short8 bf[4];
#pragma unroll
                for (int j = 0; j < 4; ++j)
                    bf[j] = *(const short8*)(Bsh + ((nh * 4 + j) * 8 + ks) * 512 + lane * 8);
#pragma unroll
                for (int j = 0; j < 4; ++j)
#pragma unroll
                    for (int mt = 0; mt < 4; ++mt)
                        acc[mt][nh * 4 + j] = __builtin_amdgcn_mfma_f32_16x16x32_bf16(
                            abuf[sl][mt], bf[j], acc[mt][nh * 4 + j], 0, 0, 0);
            }
        }

        // Epilogue: t = q*4 + j (+16*(mt&1)), h-col = nt*16+col; z: nt, f: nt+4.
        // Per-nt processing with predicated store: lane stores iff q == nt,
        // giving h = hbase + lane (coalesced within each quad's 16 lanes).
        const int cc = cgi * CPB + c;
        const size_t r0 = ((size_t)cc * BDIM + b0) * HDIM + hbase + lane;
#pragma unroll
        for (int nt = 0; nt < 4; ++nt) {
            float Aseg[4], Bseg[4];
#pragma unroll
            for (int mt = 0; mt < 4; ++mt) {
                float Ac = 1.f, Bc = 0.f;
#pragma unroll
                for (int j = 0; j < 4; ++j) {
                    float z = tanh_fast(acc[mt][nt][j] + bz[nt]);
                    float f = sigm(acc[mt][nt + 4][j] + bff[nt]);
                    Ac = f * Ac;
                    Bc = fmaf(f, Bc - z, z);       // f*Bc + (1-f)*z
                }
                Aseg[mt] = Ac; Bseg[mt] = Bc;
            }
#pragma unroll
            for (int st = 0; st < 2; ++st) {
                const int msk = 16 << st;
                const bool self_earlier = ((q >> st) & 1) == 0;
#pragma unroll
                for (int mt = 0; mt < 4; ++mt) {
                    float Ap = __shfl_xor(Aseg[mt], msk, 64);
                    float Bp = __shfl_xor(Bseg[mt], msk, 64);
                    Bseg[mt] = self_earlier ? fmaf(Ap, Bseg[mt], Bp)
                                            : fmaf(Aseg[mt], Bp, Bseg[mt]);
                    Aseg[mt] = Aseg[mt] * Ap;
                }
            }
            if (q == nt) {
                wsA[r0]        = Aseg[0] * Aseg[1];
                wsB[r0]        = fmaf(Aseg[1], Bseg[0], Bseg[1]);
                wsA[r0 + HDIM] = Aseg[2] * Aseg[3];
                wsB[r0 + HDIM] = fmaf(Aseg[3], Bseg[2], Bseg[3]);
            }
        }

#pragma unroll
        for (int mt = 0; mt < 4; ++mt)
#pragma unroll
            for (int nt = 0; nt < 8; ++nt) acc[mt][nt] = (floatx4){0.f, 0.f, 0.f, 0.f};
    }
}

// Combine chunk (A,B) pairs + o-gate at t=T-1 + output dot.
__global__ __launch_bounds__(256) void qrnn_combine(
    const float* __restrict__ wsA, const float* __restrict__ wsB,
    const float* __restrict__ c0, const int* __restrict__ X,
    const float* __restrict__ emb, const float* __restrict__ Wq,
    const float* __restrict__ bq, const float* __restrict__ Wout,
    const float* __restrict__ bout, float* __restrict__ out)
{
    const int b = blockIdx.x;
    const int h = threadIdx.x;

    float c = c0[b * HDIM + h];
    for (int c8 = 0; c8 < NC; c8 += 8) {
        float a[8], bb[8];
#pragma unroll
        for (int i = 0; i < 8; ++i) {
            size_t base = ((size_t)(c8 + i) * BDIM + b) * HDIM + h;
            a[i]  = wsA[base];
            bb[i] = wsB[base];
        }
#pragma unroll
        for (int i = 0; i < 8; ++i) c = fmaf(a[i], c, bb[i]);
    }

    __shared__ float xs[EDIM];
    int idx = X[b * TDIM + (TDIM - 1)];
    xs[h] = emb[(size_t)idx * EDIM + h];
    __syncthreads();

    float acc = 0.f;
#pragma unroll 16
    for (int e = 0; e < EDIM; ++e)
        acc = fmaf(xs[e], Wq[e * (3 * HDIM) + 2 * HDIM + h], acc);

    float o  = 1.f / (1.f + expf(-(acc + bq[2 * HDIM + h])));
    float hn = o * c;

    __shared__ float red[HDIM];
    red[h] = hn * Wout[h];
    __syncthreads();
    for (int s = HDIM / 2; s > 0; s >>= 1) {
        if (h < s) red[h] += red[h + s];
        __syncthreads();
    }
    if (h == 0) out[b] = red[0] + bout[0];
}

extern "C" void kernel_launch(void* const* d_in, const int* in_sizes, int n_in,
                              void* d_out, int out_size, void* d_ws, size_t ws_size,
                              hipStream_t stream) {
    const int*   X    = (const int*)d_in[0];
    const float* emb  = (const float*)d_in[1];
    const float* Wq   = (const float*)d_in[2];
    const float* bq   = (const float*)d_in[3];
    const float* c0   = (const float*)d_in[4];
    const float* Wout = (const float*)d_in[5];
    const float* bout = (const float*)d_in[6];
    float* out = (float*)d_out;

    float* wsA = (float*)d_ws;                        // [NC][B][H]
    float* wsB = wsA + (size_t)NC * BDIM * HDIM;      // [NC][B][H]
    unsigned short* Wp  = (unsigned short*)(wsB + (size_t)NC * BDIM * HDIM);  // 256 KB
    unsigned short* ebf = Wp + (size_t)256 * 512;     // 16.4 MB

    const size_t need_full = (size_t)2 * NC * BDIM * HDIM * 4
                           + (size_t)256 * 512 * 2
                           + (size_t)32000 * EDIM * 2;
    const bool full = ws_size >= need_full;

    const int emb_blocks = (32000 * EDIM / 8) / 256;   // 4000
    qrnn_pack<<<256 + (full ? emb_blocks : 0), 256, 0, stream>>>(Wq, emb, Wp, ebf);

    dim3 g(NC / CPB, BDIM / 8, HDIM / 64);   // 16 x 8 x 4 = 512 blocks (2/CU)
    if (full) qrnn_mfma<true ><<<g, 256, 0, stream>>>(X, emb, ebf, Wp, bq, wsA, wsB);
    else      qrnn_mfma<false><<<g, 256, 0, stream>>>(X, emb, ebf, Wp, bq, wsA, wsB);

    qrnn_combine<<<BDIM, 256, 0, stream>>>(wsA, wsB, c0, X, emb, Wq, bq, Wout, bout, out);
}

// Round 8
// 151.622 us; speedup vs baseline: 2.4739x; 1.0443x over previous
//
#include <hip/hip_runtime.h>
#include <hip/hip_bf16.h>
#include <math.h>

#define EDIM 256
#define HDIM 256
#define BDIM 64
#define TDIM 2048
#define NC   64
#define TC   32
#define CPB  4      // chunks per persistent block

typedef __attribute__((ext_vector_type(8)))  short  short8;
typedef __attribute__((ext_vector_type(4)))  float  floatx4;
typedef __attribute__((ext_vector_type(4)))  unsigned int uintx4;

__device__ __forceinline__ unsigned short f2bf(float f) {
    unsigned int u = __float_as_uint(f);
    u += 0x7FFFu + ((u >> 16) & 1u);      // RNE
    return (unsigned short)(u >> 16);
}
__device__ __forceinline__ unsigned int pk2(float a, float b) {
    return (unsigned int)f2bf(a) | ((unsigned int)f2bf(b) << 16);
}
__device__ __forceinline__ float sigm(float x) {
    return __builtin_amdgcn_rcpf(1.f + __expf(-x));
}
__device__ __forceinline__ float tanh_fast(float x) {
    return fmaf(-2.f, __builtin_amdgcn_rcpf(1.f + __expf(2.f * x)), 1.f);
}

// Fused pack: blocks [0,256) -> Wp fragment-pack; blocks [256,4256) -> emb bf16.
// Wp layout: [hg][nt][ks][lane][8] bf16; value = Wq[(ks*32+q*8+j)*768 + c],
// c = z: hg*64+(nt&3)*16+col, f: 256 + same.
__global__ __launch_bounds__(256) void qrnn_pack(
    const float* __restrict__ Wq, const float* __restrict__ emb,
    unsigned short* __restrict__ Wp, unsigned short* __restrict__ ebf)
{
    const int bx = blockIdx.x;
    if (bx < 256) {
        const int nt = (bx >> 3) & 7;
        const int hg = bx >> 6;
        const int ks = bx & 7;
        const int t = threadIdx.x;
        const int lane = t >> 2, pj = t & 3;
        const int col = lane & 15, q = lane >> 4;
        const int h = hg * 64 + (nt & 3) * 16 + col;
        const int c = (nt < 4) ? h : (HDIM + h);
        const int k = ks * 32 + q * 8 + pj * 2;
        unsigned int v = pk2(Wq[k * (3 * HDIM) + c], Wq[(k + 1) * (3 * HDIM) + c]);
        *(unsigned int*)(Wp + (size_t)bx * 512 + lane * 8 + pj * 2) = v;
    } else {
        size_t i = ((size_t)(bx - 256) * 256 + threadIdx.x) * 8;
        floatx4 a = *(const floatx4*)(emb + i);
        floatx4 b = *(const floatx4*)(emb + i + 4);
        uintx4 o = {pk2(a.x, a.y), pk2(a.z, a.w), pk2(b.x, b.y), pk2(b.z, b.w)};
        *(uintx4*)(ebf + i) = o;
    }
}

// Main: persistent block = 4 chunks x 8 batches x 64 h (128 n-cols: z||f).
// 1-D grid with XCD swizzle: bid&7 = XCD slot, bits[3:4] = hg -> the 4
// hg-siblings (identical A-rows) share an XCD's L2.
// B staged to LDS once via global_load_lds; barrier-free chunk loop.
// A gathered via SGPR-base + 32-bit voffset (no 64-bit pointer math in
// the K-loop), ring-3 / distance-2 prefetch crossing chunk boundaries.
template<bool EMBBF>
__global__ __launch_bounds__(256, 2) void qrnn_mfma(
    const int* __restrict__ X, const float* __restrict__ emb,
    const unsigned short* __restrict__ ebf, const unsigned short* __restrict__ Wp,
    const float* __restrict__ bq, float* __restrict__ wsA, float* __restrict__ wsB)
{
    __shared__ __align__(16) short Bsh[32768];   // 64 KB: [nt][ks][lane][8]

    const int tid = threadIdx.x;
    const int bid = blockIdx.x;
    const int hg  = (bid >> 3) & 3;
    const int g   = ((bid >> 5) << 3) + (bid & 7);   // 0..127
    const int cgi = g & 15, bg = g >> 4;

    const int lane = tid & 63, w = tid >> 6;
    const int col = lane & 15, q = lane >> 4;

    // Stage B slice (64 KB, all ks) once.
    const unsigned short* wpb = Wp + (size_t)hg * 32768;
#pragma unroll
    for (int i = 0; i < 16; ++i) {
        const int ch = w * 16 + i;          // wave-uniform
        __builtin_amdgcn_global_load_lds(
            (const __attribute__((address_space(1))) unsigned int*)(wpb + ch * 512 + lane * 8),
            (__attribute__((address_space(3))) unsigned int*)(Bsh + ch * 512),
            16, 0, 0);
    }

    const int b0 = bg * 8 + 2 * w;
    // 32-bit element voffsets: lane's A-fragment base in ebf/emb for (c,mt)
    unsigned int voff[CPB][4];
#pragma unroll
    for (int c = 0; c < CPB; ++c)
#pragma unroll
        for (int mt = 0; mt < 4; ++mt) {
            int xv = X[(b0 + (mt >> 1)) * TDIM + (cgi * CPB + c) * TC + (mt & 1) * 16 + col];
            voff[c][mt] = (unsigned int)xv * EDIM + q * 8;
        }

    const int hbase = hg * 64;
    float bz[4], bff[4];
#pragma unroll
    for (int nt = 0; nt < 4; ++nt) {
        bz[nt]  = bq[hbase + nt * 16 + col];
        bff[nt] = bq[HDIM + hbase + nt * 16 + col];
    }

    short8 abuf[3][4];
    auto fetchA = [&](int step, int slot) {
        const int c = step >> 3, ko = (step & 7) * 32;   // compile-time in unrolled loop
#pragma unroll
        for (int mt = 0; mt < 4; ++mt) {
            if constexpr (EMBBF) {
                abuf[slot][mt] = *(const short8*)(ebf + voff[c][mt] + ko);
            } else {
                const float* ap = emb + voff[c][mt] + ko;
                floatx4 f0 = *(const floatx4*)ap;
                floatx4 f1 = *(const floatx4*)(ap + 4);
                uintx4 p = {pk2(f0.x, f0.y), pk2(f0.z, f0.w),
                            pk2(f1.x, f1.y), pk2(f1.z, f1.w)};
                abuf[slot][mt] = *(short8*)&p;
            }
        }
    };

    floatx4 acc[4][8];
#pragma unroll
    for (int mt = 0; mt < 4; ++mt)
#pragma unroll
        for (int nt = 0; nt < 8; ++nt) acc[mt][nt] = (floatx4){0.f, 0.f, 0.f, 0.f};

    fetchA(0, 0);
    fetchA(1, 1);
    __syncthreads();   // waits LDS staging too

#pragma unroll
    for (int c = 0; c < CPB; ++c) {
#pragma unroll
        for (int ks = 0; ks < 8; ++ks) {
            const int s = c * 8 + ks;
            if (s + 2 < CPB * 8)
                fetchA(s + 2, (s + 2) % 3);
            const int sl = s % 3;
#pragma unroll
            for (int nh = 0; nh < 2; ++nh) {      // halves cut peak VGPR pressure
                short8 bf[4];
#pragma unroll
                for (int j = 0; j < 4; ++j)
                    bf[j] = *(const short8*)(Bsh + ((nh * 4 + j) * 8 + ks) * 512 + lane * 8);
#pragma unroll
                for (int j = 0; j < 4; ++j)
#pragma unroll
                    for (int mt = 0; mt < 4; ++mt)
                        acc[mt][nh * 4 + j] = __builtin_amdgcn_mfma_f32_16x16x32_bf16(
                            abuf[sl][mt], bf[j], acc[mt][nh * 4 + j], 0, 0, 0);
            }
        }

        // Epilogue (round-4 proven): t = q*4 + j (+16*(mt&1)), h-col = nt*16+col.
        const int cc = cgi * CPB + c;
        float Af0[4], Bf0[4], Af1[4], Bf1[4];
#pragma unroll
        for (int nt = 0; nt < 4; ++nt) {
            float Aseg[4], Bseg[4];
#pragma unroll
            for (int mt = 0; mt < 4; ++mt) {
                float Ac = 1.f, Bc = 0.f;
#pragma unroll
                for (int j = 0; j < 4; ++j) {
                    float z = tanh_fast(acc[mt][nt][j] + bz[nt]);
                    float f = sigm(acc[mt][nt + 4][j] + bff[nt]);
                    Ac = f * Ac;
                    Bc = fmaf(f, Bc - z, z);       // f*Bc + (1-f)*z
                }
                Aseg[mt] = Ac; Bseg[mt] = Bc;
            }
#pragma unroll
            for (int st = 0; st < 2; ++st) {
                const int msk = 16 << st;
                const bool self_earlier = ((q >> st) & 1) == 0;
#pragma unroll
                for (int mt = 0; mt < 4; ++mt) {
                    float Ap = __shfl_xor(Aseg[mt], msk, 64);
                    float Bp = __shfl_xor(Bseg[mt], msk, 64);
                    Bseg[mt] = self_earlier ? fmaf(Ap, Bseg[mt], Bp)
                                            : fmaf(Aseg[mt], Bp, Bseg[mt]);
                    Aseg[mt] = Aseg[mt] * Ap;
                }
            }
            Af0[nt] = Aseg[0] * Aseg[1];
            Bf0[nt] = fmaf(Aseg[1], Bseg[0], Bseg[1]);
            Af1[nt] = Aseg[2] * Aseg[3];
            Bf1[nt] = fmaf(Aseg[3], Bseg[2], Bseg[3]);
        }

        float As0 = (q == 0) ? Af0[0] : (q == 1) ? Af0[1] : (q == 2) ? Af0[2] : Af0[3];
        float Bs0 = (q == 0) ? Bf0[0] : (q == 1) ? Bf0[1] : (q == 2) ? Bf0[2] : Bf0[3];
        float As1 = (q == 0) ? Af1[0] : (q == 1) ? Af1[1] : (q == 2) ? Af1[2] : Af1[3];
        float Bs1 = (q == 0) ? Bf1[0] : (q == 1) ? Bf1[1] : (q == 2) ? Bf1[2] : Bf1[3];

        const size_t r0 = ((size_t)cc * BDIM + b0) * HDIM + hbase + lane;
        wsA[r0] = As0;          wsB[r0] = Bs0;
        wsA[r0 + HDIM] = As1;   wsB[r0 + HDIM] = Bs1;

#pragma unroll
        for (int mt = 0; mt < 4; ++mt)
#pragma unroll
            for (int nt = 0; nt < 8; ++nt) acc[mt][nt] = (floatx4){0.f, 0.f, 0.f, 0.f};
    }
}

// Combine chunk (A,B) pairs + o-gate at t=T-1 + output dot.
__global__ __launch_bounds__(256) void qrnn_combine(
    const float* __restrict__ wsA, const float* __restrict__ wsB,
    const float* __restrict__ c0, const int* __restrict__ X,
    const float* __restrict__ emb, const float* __restrict__ Wq,
    const float* __restrict__ bq, const float* __restrict__ Wout,
    const float* __restrict__ bout, float* __restrict__ out)
{
    const int b = blockIdx.x;
    const int h = threadIdx.x;

    float c = c0[b * HDIM + h];
    for (int c8 = 0; c8 < NC; c8 += 8) {
        float a[8], bb[8];
#pragma unroll
        for (int i = 0; i < 8; ++i) {
            size_t base = ((size_t)(c8 + i) * BDIM + b) * HDIM + h;
            a[i]  = wsA[base];
            bb[i] = wsB[base];
        }
#pragma unroll
        for (int i = 0; i < 8; ++i) c = fmaf(a[i], c, bb[i]);
    }

    __shared__ float xs[EDIM];
    int idx = X[b * TDIM + (TDIM - 1)];
    xs[h] = emb[(size_t)idx * EDIM + h];
    __syncthreads();

    float acc = 0.f;
#pragma unroll 16
    for (int e = 0; e < EDIM; ++e)
        acc = fmaf(xs[e], Wq[e * (3 * HDIM) + 2 * HDIM + h], acc);

    float o  = 1.f / (1.f + expf(-(acc + bq[2 * HDIM + h])));
    float hn = o * c;

    __shared__ float red[HDIM];
    red[h] = hn * Wout[h];
    __syncthreads();
    for (int s = HDIM / 2; s > 0; s >>= 1) {
        if (h < s) red[h] += red[h + s];
        __syncthreads();
    }
    if (h == 0) out[b] = red[0] + bout[0];
}

extern "C" void kernel_launch(void* const* d_in, const int* in_sizes, int n_in,
                              void* d_out, int out_size, void* d_ws, size_t ws_size,
                              hipStream_t stream) {
    const int*   X    = (const int*)d_in[0];
    const float* emb  = (const float*)d_in[1];
    const float* Wq   = (const float*)d_in[2];
    const float* bq   = (const float*)d_in[3];
    const float* c0   = (const float*)d_in[4];
    const float* Wout = (const float*)d_in[5];
    const float* bout = (const float*)d_in[6];
    float* out = (float*)d_out;

    float* wsA = (float*)d_ws;                        // [NC][B][H]
    float* wsB = wsA + (size_t)NC * BDIM * HDIM;      // [NC][B][H]
    unsigned short* Wp  = (unsigned short*)(wsB + (size_t)NC * BDIM * HDIM);  // 256 KB
    unsigned short* ebf = Wp + (size_t)256 * 512;     // 16.4 MB

    const size_t need_full = (size_t)2 * NC * BDIM * HDIM * 4
                           + (size_t)256 * 512 * 2
                           + (size_t)32000 * EDIM * 2;
    const bool full = ws_size >= need_full;

    const int emb_blocks = (32000 * EDIM / 8) / 256;   // 4000
    qrnn_pack<<<256 + (full ? emb_blocks : 0), 256, 0, stream>>>(Wq, emb, Wp, ebf);

    if (full) qrnn_mfma<true ><<<512, 256, 0, stream>>>(X, emb, ebf, Wp, bq, wsA, wsB);
    else      qrnn_mfma<false><<<512, 256, 0, stream>>>(X, emb, ebf, Wp, bq, wsA, wsB);

    qrnn_combine<<<BDIM, 256, 0, stream>>>(wsA, wsB, c0, X, emb, Wq, bq, Wout, bout, out);
}